// Round 2
// baseline (354.823 us; speedup 1.0000x reference)
//
#include <hip/hip_runtime.h>

typedef unsigned short ushort_t;
typedef unsigned int uint32;

#define N_NODES 10000
#define N_EDGES 160000
#define ET (N_NODES + N_EDGES)   /* 170000 edges incl self-loops */
#define MPAD 10112               /* 79 * 128 */
#define HT 1024                  /* heads * hid */
#define HEADS 8
#define NEG 0.2f

/* ---- ws layout (bytes, 256-aligned) ---- */
#define O_FLAG     0             /* flags[0]=edge64, flags[1]=inputs_f32 */
#define O_SRC      256
#define O_DST      (O_SRC + 680192)
#define O_COUNTS   (O_DST + 680192)
#define O_OFFS     (O_COUNTS + 40192)
#define O_CURS     (O_OFFS + 40192)
#define O_SSORT    (O_CURS + 40192)
#define O_ALS      (O_SSORT + 680192)
#define O_ALD      (O_ALS + 320000)
#define O_AL3S     (O_ALD + 320000)
#define O_AL3D     (O_AL3S + 40192)
#define O_H3       (O_AL3D + 40192)
#define O_XF       (O_H3 + 160000)      /* x fp32: 140000 floats */
#define O_W1F      (O_XF + 560128)      /* 14336 floats */
#define O_AS1F     (O_W1F + 57344)      /* 6 x 1024 floats: as1,ad1,b1,as2,ad2,b2 */
#define O_W3F      (O_AS1F + 24576)     /* 4096 floats */
#define O_S3F      (O_W3F + 16384)      /* as3(4)+ad3(4)+b3(4), 256 each */
#define O_W2T      (O_S3F + 768)        /* bf16 [1024,1024] transposed */
#define O_BUFA     (O_W2T + 2097152)
#define O_BUFB     (O_BUFA + 20709376)

__device__ __forceinline__ float bf2f(ushort_t u){ return __uint_as_float(((uint32)u) << 16); }
__device__ __forceinline__ ushort_t f2bf(float f){
    uint32 x = __float_as_uint(f);
    return (ushort_t)((x + 0x7fffu + ((x >> 16) & 1u)) >> 16);
}
__device__ __forceinline__ void unpack2(uint32 u, float& lo, float& hi){
    lo = __uint_as_float(u << 16);
    hi = __uint_as_float(u & 0xffff0000u);
}

typedef __bf16 bf16x8 __attribute__((ext_vector_type(8)));
typedef float  f32x4  __attribute__((ext_vector_type(4)));

typedef const __attribute__((address_space(1))) uint32* gas1_u32;
typedef       __attribute__((address_space(3))) uint32* las3_u32;

__device__ __forceinline__ void gload_lds16(const void* g, void* l){
    __builtin_amdgcn_global_load_lds((gas1_u32)g, (las3_u32)l, 16, 0, 0);
}

/* ---------------- probes: edge dtype (int64 odd words zero) + input dtype ----------------
   fp32 gaussian arrays: low 16 bits of each word are mantissa bits -> exponent-field
   (bits 14..7) uniform over 0..255 -> ~38% land in [64,160].
   bf16 arrays: low element IS a bf16 value with exponent concentrated near 127 ->
   ~100% land in [64,160]. */
__global__ void k_probe(const int* __restrict__ ei, const uint32* __restrict__ w1raw,
                        int* __restrict__ flags){
    if (threadIdx.x == 0){
        int nz = 0;
        for (int i = 0; i < 128; i++) nz |= ei[2*i + 1];
        flags[0] = (nz == 0) ? 1 : 0;
    }
    if (threadIdx.x == 1){
        int cnt = 0;
        for (int i = 0; i < 256; i++){
            uint32 e = (w1raw[i] >> 7) & 0xffu;
            cnt += (e >= 64u && e <= 160u) ? 1 : 0;
        }
        flags[1] = (cnt > 200) ? 0 : 1;   /* 1 = inputs are fp32 */
    }
}

/* ---------------- convert inputs to canonical fp32 ---------------- */
struct CvtArgs {
    const void* src[12];
    float*      dst[12];
    int         n[12];
};

__global__ __launch_bounds__(256) void k_cvt(CvtArgs a, const int* __restrict__ flags){
    int aid = blockIdx.y;
    int n = a.n[aid];
    int base = blockIdx.x * 1024 + threadIdx.x * 4;
    if (base >= n) return;
    int f32 = flags[1];
    const void* s = a.src[aid];
    float* d = a.dst[aid];
    #pragma unroll
    for (int j = 0; j < 4; j++){
        int i = base + j;
        if (i < n){
            d[i] = f32 ? ((const float*)s)[i] : bf2f(((const ushort_t*)s)[i]);
        }
    }
}

/* ---------------- extract edges (+self-loops) as int32 ---------------- */
__global__ __launch_bounds__(256) void k_extract(const void* __restrict__ ei, const int* __restrict__ flags,
                                                 int* __restrict__ src, int* __restrict__ dst){
    int i = blockIdx.x * 256 + threadIdx.x;
    int is64 = flags[0];
    if (i < N_EDGES){
        if (is64){
            const long long* p = (const long long*)ei;
            src[i] = (int)p[i]; dst[i] = (int)p[N_EDGES + i];
        } else {
            const int* p = (const int*)ei;
            src[i] = p[i]; dst[i] = p[N_EDGES + i];
        }
    } else if (i < ET){
        int n = i - N_EDGES;
        src[i] = n; dst[i] = n;
    }
}

__global__ __launch_bounds__(256) void k_hist(const int* __restrict__ dst, int* __restrict__ counts){
    int i = blockIdx.x * 256 + threadIdx.x;
    if (i < ET) atomicAdd(&counts[dst[i]], 1);
}

/* single-block exclusive scan over N_NODES counts -> offs + cursors */
__global__ __launch_bounds__(1024) void k_scan(const int* __restrict__ counts, int* __restrict__ offs,
                                               int* __restrict__ cursors, int n){
    __shared__ int wsum[16];
    __shared__ int running_s;
    int tid = threadIdx.x;
    int lane = tid & 63, wid = tid >> 6;
    if (tid == 0) running_s = 0;
    __syncthreads();
    for (int base = 0; base < n; base += 1024){
        int i = base + tid;
        int v = (i < n) ? counts[i] : 0;
        int x = v;
        #pragma unroll
        for (int d = 1; d < 64; d <<= 1){
            int t = __shfl_up(x, d, 64);
            if (lane >= d) x += t;
        }
        if (lane == 63) wsum[wid] = x;
        __syncthreads();
        if (wid == 0 && lane < 16){
            int w = wsum[lane];
            #pragma unroll
            for (int d = 1; d < 16; d <<= 1){
                int t = __shfl_up(w, d, 64);
                if (lane >= d) w += t;
            }
            wsum[lane] = w;
        }
        __syncthreads();
        int wprefix = (wid == 0) ? 0 : wsum[wid - 1];
        int run = running_s;
        int excl = run + wprefix + (x - v);
        if (i < n){ offs[i] = excl; cursors[i] = excl; }
        __syncthreads();
        if (tid == 0) running_s = run + wsum[15];
        __syncthreads();
    }
    if (tid == 0) offs[n] = running_s;
}

__global__ __launch_bounds__(256) void k_scatter(const int* __restrict__ src, const int* __restrict__ dst,
                                                 int* __restrict__ cursors, int* __restrict__ ssort){
    int i = blockIdx.x * 256 + threadIdx.x;
    if (i < ET){
        int pos = atomicAdd(&cursors[dst[i]], 1);
        ssort[pos] = src[i];
    }
}

/* ---------------- layer-1 GEMM: [10000,14] x [14,1024] -> bf16 ---------------- */
__global__ __launch_bounds__(256) void k_gemm1(const float* __restrict__ x, const float* __restrict__ W1,
                                               ushort_t* __restrict__ h1){
    int n = blockIdx.x;
    int tid = threadIdx.x;
    __shared__ float xs[14];
    if (tid < 14) xs[tid] = x[n*14 + tid];
    __syncthreads();
    int c0 = tid * 4;
    float a0=0.f, a1=0.f, a2=0.f, a3=0.f;
    for (int k = 0; k < 14; k++){
        float xv = xs[k];
        float4 w = *(const float4*)(W1 + (size_t)k*HT + c0);
        a0 += xv*w.x; a1 += xv*w.y; a2 += xv*w.z; a3 += xv*w.w;
    }
    uint2 o;
    o.x = (uint32)f2bf(a0) | ((uint32)f2bf(a1) << 16);
    o.y = (uint32)f2bf(a2) | ((uint32)f2bf(a3) << 16);
    *(uint2*)(h1 + (size_t)n*HT + c0) = o;
}

/* ---------------- per-node attention logit dots: alS/alD [N,8] ---------------- */
__global__ __launch_bounds__(256) void k_alpha(const ushort_t* __restrict__ H, const float* __restrict__ a_src,
                                               const float* __restrict__ a_dst,
                                               float* __restrict__ alS, float* __restrict__ alD){
    int n = blockIdx.x, tid = threadIdx.x;
    int idx = tid * 4;
    uint2 hv = *(const uint2*)(H + (size_t)n*HT + idx);
    float4 sv = *(const float4*)(a_src + idx);
    float4 dv = *(const float4*)(a_dst + idx);
    float h0,h1,h2,h3;
    unpack2(hv.x, h0, h1); unpack2(hv.y, h2, h3);
    float s = h0*sv.x + h1*sv.y + h2*sv.z + h3*sv.w;
    float d = h0*dv.x + h1*dv.y + h2*dv.z + h3*dv.w;
    #pragma unroll
    for (int o = 16; o; o >>= 1){ s += __shfl_xor(s, o, 32); d += __shfl_xor(d, o, 32); }
    if ((tid & 31) == 0){ int head = tid >> 5; alS[n*HEADS + head] = s; alD[n*HEADS + head] = d; }
}

/* ---------------- fused segment-softmax + aggregate + bias + relu ---------------- */
__global__ __launch_bounds__(256) void k_gat_agg(const ushort_t* __restrict__ H, const float* __restrict__ alS,
                                                 const float* __restrict__ alD, const int* __restrict__ offs,
                                                 const int* __restrict__ srcs, const float* __restrict__ bias,
                                                 ushort_t* __restrict__ out){
    int n = blockIdx.x;
    int tid = threadIdx.x;
    int head = tid >> 5;
    int l32 = tid & 31;
    int beg = offs[n], end = offs[n+1];
    float ad = alD[n*HEADS + head];
    __shared__ float sm[HEADS], sz[HEADS];
    float m = -1e30f;
    for (int e = beg + l32; e < end; e += 32){
        int s = srcs[e];
        float v = alS[s*HEADS + head] + ad;
        v = v > 0.f ? v : NEG*v;
        m = fmaxf(m, v);
    }
    #pragma unroll
    for (int o = 16; o; o >>= 1) m = fmaxf(m, __shfl_xor(m, o, 32));
    float z = 0.f;
    for (int e = beg + l32; e < end; e += 32){
        int s = srcs[e];
        float v = alS[s*HEADS + head] + ad;
        v = v > 0.f ? v : NEG*v;
        z += __expf(v - m);
    }
    #pragma unroll
    for (int o = 16; o; o >>= 1) z += __shfl_xor(z, o, 32);
    if (l32 == 0){ sm[head] = m; sz[head] = z; }
    __syncthreads();
    float mh = sm[head];
    float inv = 1.f / (sz[head] + 1e-16f);
    int ch = tid * 4;
    float a0=0.f, a1=0.f, a2=0.f, a3=0.f;
    for (int e = beg; e < end; ++e){
        int s = srcs[e];
        float v = alS[s*HEADS + head] + ad;
        v = v > 0.f ? v : NEG*v;
        float w = __expf(v - mh) * inv;
        uint2 hv = *(const uint2*)(H + (size_t)s*HT + ch);
        float f0,f1,f2,f3;
        unpack2(hv.x, f0, f1); unpack2(hv.y, f2, f3);
        a0 += w*f0; a1 += w*f1; a2 += w*f2; a3 += w*f3;
    }
    float4 bv = *(const float4*)(bias + ch);
    a0 = fmaxf(a0 + bv.x, 0.f); a1 = fmaxf(a1 + bv.y, 0.f);
    a2 = fmaxf(a2 + bv.z, 0.f); a3 = fmaxf(a3 + bv.w, 0.f);
    uint2 o;
    o.x = (uint32)f2bf(a0) | ((uint32)f2bf(a1) << 16);
    o.y = (uint32)f2bf(a2) | ((uint32)f2bf(a3) << 16);
    *(uint2*)(out + (size_t)n*HT + ch) = o;
}

/* ---------------- transpose W2 [1024,1024] -> bf16 [N,K] ---------------- */
__global__ __launch_bounds__(256) void k_transpose(const void* __restrict__ in, const int* __restrict__ flags,
                                                   ushort_t* __restrict__ out){
    __shared__ ushort_t tile[32][33];
    int f32 = flags[1];
    int bx = blockIdx.x, by = blockIdx.y;
    int cx = threadIdx.x & 31;
    int ry = (threadIdx.x >> 5) * 4;
    #pragma unroll
    for (int r = 0; r < 4; r++){
        size_t idx = (size_t)(by*32 + ry + r)*1024 + bx*32 + cx;
        tile[ry + r][cx] = f32 ? f2bf(((const float*)in)[idx]) : ((const ushort_t*)in)[idx];
    }
    __syncthreads();
    #pragma unroll
    for (int r = 0; r < 4; r++)
        out[(size_t)(bx*32 + ry + r)*1024 + by*32 + cx] = tile[cx][ry + r];
}

/* ---------------- layer-2 GEMM: bf16 MFMA, A[MPAD,1024] x BT[1024,1024]^T ---------------- */
__global__ __launch_bounds__(256) void k_gemm2(const ushort_t* __restrict__ A, const ushort_t* __restrict__ BT,
                                               ushort_t* __restrict__ C){
    __shared__ ushort_t lA[128*32];
    __shared__ ushort_t lB[128*32];
    int tid = threadIdx.x;
    int bm = blockIdx.x, bn = blockIdx.y;
    int lane = tid & 63;
    int wave = tid >> 6;
    int wm = (wave & 1) * 64, wn = (wave >> 1) * 64;
    int lm = lane & 15, kg = lane >> 4;
    f32x4 acc[4][4];
    #pragma unroll
    for (int i = 0; i < 4; i++)
        #pragma unroll
        for (int j = 0; j < 4; j++) acc[i][j] = (f32x4)0.0f;

    const int K = 1024;
    int rowA0 = bm * 128, rowB0 = bn * 128;
    for (int k0 = 0; k0 < K; k0 += 32){
        #pragma unroll
        for (int it = 0; it < 2; ++it){
            int s = tid + it*256;
            int r = s >> 2, ks = s & 3;
            gload_lds16(A  + (size_t)(rowA0 + r)*K + k0 + ks*8, lA + s*8);
            gload_lds16(BT + (size_t)(rowB0 + r)*K + k0 + ks*8, lB + s*8);
        }
        __syncthreads();
        bf16x8 af[4], bfr[4];
        #pragma unroll
        for (int mt = 0; mt < 4; mt++) af[mt]  = *(const bf16x8*)(lA + (wm + mt*16 + lm)*32 + kg*8);
        #pragma unroll
        for (int nt = 0; nt < 4; nt++) bfr[nt] = *(const bf16x8*)(lB + (wn + nt*16 + lm)*32 + kg*8);
        #pragma unroll
        for (int mt = 0; mt < 4; mt++)
            #pragma unroll
            for (int nt = 0; nt < 4; nt++)
                acc[mt][nt] = __builtin_amdgcn_mfma_f32_16x16x32_bf16(af[mt], bfr[nt], acc[mt][nt], 0, 0, 0);
        __syncthreads();
    }
    #pragma unroll
    for (int mt = 0; mt < 4; mt++){
        int row_base = bm*128 + wm + mt*16 + kg*4;
        #pragma unroll
        for (int nt = 0; nt < 4; nt++){
            int col = bn*128 + wn + nt*16 + lm;
            #pragma unroll
            for (int r = 0; r < 4; r++){
                int row = row_base + r;
                if (row < N_NODES) C[(size_t)row*HT + col] = f2bf(acc[mt][nt][r]);
            }
        }
    }
}

/* ---------------- layer-3 GEMM (K=1024, 4 cols) + al3 dots ---------------- */
__global__ __launch_bounds__(256) void k_gemm3(const ushort_t* __restrict__ A, const float* __restrict__ W3,
                                               const float* __restrict__ s3, /* as3[4],ad3 at +64,b3 unused here */
                                               float* __restrict__ h3, float* __restrict__ al3s, float* __restrict__ al3d){
    int n = blockIdx.x;
    int tid = threadIdx.x;
    float acc[4] = {0.f, 0.f, 0.f, 0.f};
    uint2 av = *(const uint2*)(A + (size_t)n*HT + tid*4);
    float a[4];
    unpack2(av.x, a[0], a[1]); unpack2(av.y, a[2], a[3]);
    #pragma unroll
    for (int j = 0; j < 4; j++){
        float4 w = ((const float4*)W3)[tid*4 + j];
        acc[0] += a[j]*w.x; acc[1] += a[j]*w.y; acc[2] += a[j]*w.z; acc[3] += a[j]*w.w;
    }
    #pragma unroll
    for (int o = 32; o; o >>= 1){
        #pragma unroll
        for (int c = 0; c < 4; c++) acc[c] += __shfl_xor(acc[c], o, 64);
    }
    __shared__ float part[4][4];
    int wave = tid >> 6, lane = tid & 63;
    if (lane == 0){
        #pragma unroll
        for (int c = 0; c < 4; c++) part[wave][c] = acc[c];
    }
    __syncthreads();
    if (tid == 0){
        float s = 0.f, d = 0.f;
        #pragma unroll
        for (int c = 0; c < 4; c++){
            float h = part[0][c] + part[1][c] + part[2][c] + part[3][c];
            h3[n*4 + c] = h;
            s += h * s3[c];        /* as3 */
            d += h * s3[16 + c];   /* ad3 at +64 bytes */
        }
        al3s[n] = s; al3d[n] = d;
    }
}

/* ---------------- layer-3 attention aggregate -> final output ---------------- */
__global__ __launch_bounds__(64) void k_gat_agg3(const float* __restrict__ h3, const float* __restrict__ al3s,
                                                 const float* __restrict__ al3d, const int* __restrict__ offs,
                                                 const int* __restrict__ srcs, const float* __restrict__ b3,
                                                 const int* __restrict__ flags, void* __restrict__ out){
    int n = blockIdx.x;
    int l = threadIdx.x;
    int beg = offs[n], end = offs[n+1];
    float ad = al3d[n];
    float m = -1e30f;
    for (int e = beg + l; e < end; e += 64){
        float v = al3s[srcs[e]] + ad; v = v > 0.f ? v : NEG*v;
        m = fmaxf(m, v);
    }
    #pragma unroll
    for (int o = 32; o; o >>= 1) m = fmaxf(m, __shfl_xor(m, o, 64));
    float z = 0.f;
    for (int e = beg + l; e < end; e += 64){
        float v = al3s[srcs[e]] + ad; v = v > 0.f ? v : NEG*v;
        z += __expf(v - m);
    }
    #pragma unroll
    for (int o = 32; o; o >>= 1) z += __shfl_xor(z, o, 64);
    float inv = 1.f / (z + 1e-16f);
    float a0=0.f, a1=0.f, a2=0.f, a3=0.f;
    for (int e = beg + l; e < end; e += 64){
        int s = srcs[e];
        float v = al3s[s] + ad; v = v > 0.f ? v : NEG*v;
        float w = __expf(v - m) * inv;
        a0 += w*h3[s*4+0]; a1 += w*h3[s*4+1]; a2 += w*h3[s*4+2]; a3 += w*h3[s*4+3];
    }
    #pragma unroll
    for (int o = 32; o; o >>= 1){
        a0 += __shfl_xor(a0, o, 64); a1 += __shfl_xor(a1, o, 64);
        a2 += __shfl_xor(a2, o, 64); a3 += __shfl_xor(a3, o, 64);
    }
    if (l == 0){
        float r0 = fmaxf(a0 + b3[0], 0.f);
        float r1 = fmaxf(a1 + b3[1], 0.f);
        float r2 = fmaxf(a2 + b3[2], 0.f);
        float r3 = fmaxf(a3 + b3[3], 0.f);
        if (flags[1]){
            float* o4 = (float*)out;
            o4[n*4+0]=r0; o4[n*4+1]=r1; o4[n*4+2]=r2; o4[n*4+3]=r3;
        } else {
            ushort_t* o2 = (ushort_t*)out;
            o2[n*4+0]=f2bf(r0); o2[n*4+1]=f2bf(r1); o2[n*4+2]=f2bf(r2); o2[n*4+3]=f2bf(r3);
        }
    }
}

extern "C" void kernel_launch(void* const* d_in, const int* in_sizes, int n_in,
                              void* d_out, int out_size, void* d_ws, size_t ws_size,
                              hipStream_t stream){
    const void* x   = d_in[0];
    const void* ei  = d_in[1];
    const void* W1  = d_in[2];
    const void* as1 = d_in[3];
    const void* ad1 = d_in[4];
    const void* b1  = d_in[5];
    const void* W2  = d_in[6];
    const void* as2 = d_in[7];
    const void* ad2 = d_in[8];
    const void* b2  = d_in[9];
    const void* W3  = d_in[10];
    const void* as3 = d_in[11];
    const void* ad3 = d_in[12];
    const void* b3  = d_in[13];

    char* ws = (char*)d_ws;
    int* flags     = (int*)(ws + O_FLAG);
    int* srcA      = (int*)(ws + O_SRC);
    int* dstA      = (int*)(ws + O_DST);
    int* counts    = (int*)(ws + O_COUNTS);
    int* offs      = (int*)(ws + O_OFFS);
    int* cursors   = (int*)(ws + O_CURS);
    int* ssort     = (int*)(ws + O_SSORT);
    float* alS     = (float*)(ws + O_ALS);
    float* alD     = (float*)(ws + O_ALD);
    float* al3s    = (float*)(ws + O_AL3S);
    float* al3d    = (float*)(ws + O_AL3D);
    float* h3      = (float*)(ws + O_H3);
    float* xF      = (float*)(ws + O_XF);
    float* W1F     = (float*)(ws + O_W1F);
    float* wvecF   = (float*)(ws + O_AS1F);  /* as1,ad1,b1,as2,ad2,b2 @ 1024 floats each */
    float* W3F     = (float*)(ws + O_W3F);
    float* s3F     = (float*)(ws + O_S3F);   /* as3 @0, ad3 @64, b3 @128 floats */
    ushort_t* W2T  = (ushort_t*)(ws + O_W2T);
    ushort_t* bufA = (ushort_t*)(ws + O_BUFA);   /* h1 / h2 */
    ushort_t* bufB = (ushort_t*)(ws + O_BUFB);   /* agg1 / agg2, MPAD rows */

    const int EB = (ET + 255) / 256;

    k_probe<<<1, 64, 0, stream>>>((const int*)ei, (const uint32*)W1, flags);

    CvtArgs ca;
    ca.src[0]=x;   ca.dst[0]=xF;          ca.n[0]=140000;
    ca.src[1]=W1;  ca.dst[1]=W1F;         ca.n[1]=14336;
    ca.src[2]=as1; ca.dst[2]=wvecF+0*1024;  ca.n[2]=1024;
    ca.src[3]=ad1; ca.dst[3]=wvecF+1*1024;  ca.n[3]=1024;
    ca.src[4]=b1;  ca.dst[4]=wvecF+2*1024;  ca.n[4]=1024;
    ca.src[5]=as2; ca.dst[5]=wvecF+3*1024;  ca.n[5]=1024;
    ca.src[6]=ad2; ca.dst[6]=wvecF+4*1024;  ca.n[6]=1024;
    ca.src[7]=b2;  ca.dst[7]=wvecF+5*1024;  ca.n[7]=1024;
    ca.src[8]=W3;  ca.dst[8]=W3F;         ca.n[8]=4096;
    ca.src[9]=as3; ca.dst[9]=s3F+0;       ca.n[9]=4;
    ca.src[10]=ad3; ca.dst[10]=s3F+16;    ca.n[10]=4;
    ca.src[11]=b3;  ca.dst[11]=s3F+32;    ca.n[11]=4;
    k_cvt<<<dim3(137, 12), 256, 0, stream>>>(ca, flags);

    k_extract<<<EB, 256, 0, stream>>>(ei, flags, srcA, dstA);
    hipMemsetAsync(counts, 0, N_NODES*sizeof(int), stream);
    k_hist<<<EB, 256, 0, stream>>>(dstA, counts);
    k_scan<<<1, 1024, 0, stream>>>(counts, offs, cursors, N_NODES);
    k_scatter<<<EB, 256, 0, stream>>>(srcA, dstA, cursors, ssort);

    /* layer 1 */
    k_gemm1<<<N_NODES, 256, 0, stream>>>(xF, W1F, bufA);
    k_alpha<<<N_NODES, 256, 0, stream>>>(bufA, wvecF+0*1024, wvecF+1*1024, alS, alD);
    k_gat_agg<<<N_NODES, 256, 0, stream>>>(bufA, alS, alD, offs, ssort, wvecF+2*1024, bufB);

    /* layer 2 */
    k_transpose<<<dim3(32, 32), 256, 0, stream>>>(W2, flags, W2T);
    k_gemm2<<<dim3(79, 8), 256, 0, stream>>>(bufB, W2T, bufA);
    k_alpha<<<N_NODES, 256, 0, stream>>>(bufA, wvecF+3*1024, wvecF+4*1024, alS, alD);
    k_gat_agg<<<N_NODES, 256, 0, stream>>>(bufA, alS, alD, offs, ssort, wvecF+5*1024, bufB);

    /* layer 3 */
    k_gemm3<<<N_NODES, 256, 0, stream>>>(bufB, W3F, s3F, h3, al3s, al3d);
    k_gat_agg3<<<N_NODES, 64, 0, stream>>>(h3, al3s, al3d, offs, ssort, s3F+32, flags, d_out);
}

// Round 3
// 334.467 us; speedup vs baseline: 1.0609x; 1.0609x over previous
//
#include <hip/hip_runtime.h>

typedef unsigned short ushort_t;
typedef unsigned int uint32;

#define N_NODES 10000
#define N_EDGES 160000
#define ET (N_NODES + N_EDGES)   /* 170000 edges incl self-loops */
#define MPAD 10112               /* 79 * 128 */
#define HT 1024                  /* heads * hid */
#define HEADS 8
#define NEG 0.2f
#define AGG_CH 64                /* edge chunk for agg weight precompute */

/* ---- ws layout (bytes, 256-aligned) ---- */
#define O_FLAG     0             /* flags[0]=edge64, flags[1]=inputs_f32 */
#define O_SRC      256
#define O_DST      (O_SRC + 680192)
#define O_COUNTS   (O_DST + 680192)
#define O_OFFS     (O_COUNTS + 40192)
#define O_CURS     (O_OFFS + 40192)
#define O_SSORT    (O_CURS + 40192)
#define O_ALS      (O_SSORT + 680192)
#define O_ALD      (O_ALS + 320000)
#define O_AL3S     (O_ALD + 320000)
#define O_AL3D     (O_AL3S + 40192)
#define O_H3       (O_AL3D + 40192)
#define O_XF       (O_H3 + 160000)      /* x fp32: 140000 floats */
#define O_W1F      (O_XF + 560128)      /* 14336 floats */
#define O_AS1F     (O_W1F + 57344)      /* 6 x 1024 floats: as1,ad1,b1,as2,ad2,b2 */
#define O_W3F      (O_AS1F + 24576)     /* 4096 floats */
#define O_S3F      (O_W3F + 16384)      /* as3 @0, ad3 @+16 floats, b3 @+32 floats */
#define O_W2T      (O_S3F + 768)        /* bf16 [1024,1024] transposed */
#define O_BUFA     (O_W2T + 2097152)
#define O_BUFB     (O_BUFA + 20709376)

__device__ __forceinline__ float bf2f(ushort_t u){ return __uint_as_float(((uint32)u) << 16); }
__device__ __forceinline__ ushort_t f2bf(float f){
    uint32 x = __float_as_uint(f);
    return (ushort_t)((x + 0x7fffu + ((x >> 16) & 1u)) >> 16);
}
__device__ __forceinline__ void unpack2(uint32 u, float& lo, float& hi){
    lo = __uint_as_float(u << 16);
    hi = __uint_as_float(u & 0xffff0000u);
}

typedef __bf16 bf16x8 __attribute__((ext_vector_type(8)));
typedef float  f32x4  __attribute__((ext_vector_type(4)));

typedef const __attribute__((address_space(1))) uint32* gas1_u32;
typedef       __attribute__((address_space(3))) uint32* las3_u32;

__device__ __forceinline__ void gload_lds16(const void* g, void* l){
    __builtin_amdgcn_global_load_lds((gas1_u32)g, (las3_u32)l, 16, 0, 0);
}

/* ---------------- probes: edge dtype + input dtype ---------------- */
__global__ void k_probe(const int* __restrict__ ei, const uint32* __restrict__ w1raw,
                        int* __restrict__ flags){
    if (threadIdx.x == 0){
        int nz = 0;
        for (int i = 0; i < 128; i++) nz |= ei[2*i + 1];
        flags[0] = (nz == 0) ? 1 : 0;
    }
    if (threadIdx.x == 1){
        int cnt = 0;
        for (int i = 0; i < 256; i++){
            uint32 e = (w1raw[i] >> 7) & 0xffu;
            cnt += (e >= 64u && e <= 160u) ? 1 : 0;
        }
        flags[1] = (cnt > 200) ? 0 : 1;   /* 1 = inputs are fp32 */
    }
}

/* ---------------- convert inputs to canonical fp32 ---------------- */
struct CvtArgs {
    const void* src[12];
    float*      dst[12];
    int         n[12];
};

__global__ __launch_bounds__(256) void k_cvt(CvtArgs a, const int* __restrict__ flags){
    int aid = blockIdx.y;
    int n = a.n[aid];
    int base = blockIdx.x * 1024 + threadIdx.x * 4;
    if (base >= n) return;
    int f32 = flags[1];
    const void* s = a.src[aid];
    float* d = a.dst[aid];
    #pragma unroll
    for (int j = 0; j < 4; j++){
        int i = base + j;
        if (i < n){
            d[i] = f32 ? ((const float*)s)[i] : bf2f(((const ushort_t*)s)[i]);
        }
    }
}

/* ---------------- extract edges (+self-loops) as int32, fused histogram ---------------- */
__global__ __launch_bounds__(256) void k_extract_hist(const void* __restrict__ ei, const int* __restrict__ flags,
                                                      int* __restrict__ src, int* __restrict__ dst,
                                                      int* __restrict__ counts){
    int i = blockIdx.x * 256 + threadIdx.x;
    int is64 = flags[0];
    int s = -1, d = -1;
    if (i < N_EDGES){
        if (is64){
            const long long* p = (const long long*)ei;
            s = (int)p[i]; d = (int)p[N_EDGES + i];
        } else {
            const int* p = (const int*)ei;
            s = p[i]; d = p[N_EDGES + i];
        }
    } else if (i < ET){
        s = i - N_EDGES; d = s;
    }
    if (d >= 0){
        src[i] = s; dst[i] = d;
        atomicAdd(&counts[d], 1);
    }
}

/* single-block exclusive scan over N_NODES counts -> offs + cursors */
__global__ __launch_bounds__(1024) void k_scan(const int* __restrict__ counts, int* __restrict__ offs,
                                               int* __restrict__ cursors, int n){
    __shared__ int wsum[16];
    __shared__ int running_s;
    int tid = threadIdx.x;
    int lane = tid & 63, wid = tid >> 6;
    if (tid == 0) running_s = 0;
    __syncthreads();
    for (int base = 0; base < n; base += 1024){
        int i = base + tid;
        int v = (i < n) ? counts[i] : 0;
        int x = v;
        #pragma unroll
        for (int d = 1; d < 64; d <<= 1){
            int t = __shfl_up(x, d, 64);
            if (lane >= d) x += t;
        }
        if (lane == 63) wsum[wid] = x;
        __syncthreads();
        if (wid == 0 && lane < 16){
            int w = wsum[lane];
            #pragma unroll
            for (int d = 1; d < 16; d <<= 1){
                int t = __shfl_up(w, d, 64);
                if (lane >= d) w += t;
            }
            wsum[lane] = w;
        }
        __syncthreads();
        int wprefix = (wid == 0) ? 0 : wsum[wid - 1];
        int run = running_s;
        int excl = run + wprefix + (x - v);
        if (i < n){ offs[i] = excl; cursors[i] = excl; }
        __syncthreads();
        if (tid == 0) running_s = run + wsum[15];
        __syncthreads();
    }
    if (tid == 0) offs[n] = running_s;
}

__global__ __launch_bounds__(256) void k_scatter(const int* __restrict__ src, const int* __restrict__ dst,
                                                 int* __restrict__ cursors, int* __restrict__ ssort){
    int i = blockIdx.x * 256 + threadIdx.x;
    if (i < ET){
        int pos = atomicAdd(&cursors[dst[i]], 1);
        ssort[pos] = src[i];
    }
}

/* ---------------- layer-1 GEMM fused with attention dots ----------------
   512 persistent blocks; W1 (14x1024 fp32, 56KB) staged in LDS once;
   each block loops nodes. Also emits alS/alD (fuses old k_alpha for L1). */
__global__ __launch_bounds__(256) void k_gemm1f(const float* __restrict__ x, const float* __restrict__ W1,
                                                const float* __restrict__ a_src, const float* __restrict__ a_dst,
                                                ushort_t* __restrict__ h1,
                                                float* __restrict__ alS, float* __restrict__ alD){
    __shared__ float w1s[14 * HT];
    int tid = threadIdx.x;
    for (int i = tid * 4; i < 14 * HT; i += 1024)
        *(float4*)(w1s + i) = *(const float4*)(W1 + i);
    int c0 = tid * 4;
    float4 sv = *(const float4*)(a_src + c0);
    float4 dv = *(const float4*)(a_dst + c0);
    int head = tid >> 5, l32 = tid & 31;
    __syncthreads();
    for (int n = blockIdx.x; n < N_NODES; n += gridDim.x){
        float a0=0.f, a1=0.f, a2=0.f, a3=0.f;
        #pragma unroll
        for (int k = 0; k < 14; k++){
            float xv = x[n*14 + k];
            float4 w = *(const float4*)(w1s + k*HT + c0);
            a0 += xv*w.x; a1 += xv*w.y; a2 += xv*w.z; a3 += xv*w.w;
        }
        uint2 o;
        o.x = (uint32)f2bf(a0) | ((uint32)f2bf(a1) << 16);
        o.y = (uint32)f2bf(a2) | ((uint32)f2bf(a3) << 16);
        *(uint2*)(h1 + (size_t)n*HT + c0) = o;
        /* attention dots on bf16-rounded h (matches downstream dataflow) */
        float h0,h1v,h2,h3v;
        unpack2(o.x, h0, h1v); unpack2(o.y, h2, h3v);
        float s = h0*sv.x + h1v*sv.y + h2*sv.z + h3v*sv.w;
        float d = h0*dv.x + h1v*dv.y + h2*dv.z + h3v*dv.w;
        #pragma unroll
        for (int of = 16; of; of >>= 1){ s += __shfl_xor(s, of, 32); d += __shfl_xor(d, of, 32); }
        if (l32 == 0){ alS[n*HEADS + head] = s; alD[n*HEADS + head] = d; }
    }
}

/* ---------------- layer-2 attention dots, 16 nodes/block ---------------- */
__global__ __launch_bounds__(256) void k_alpha2(const ushort_t* __restrict__ H, const float* __restrict__ a_src,
                                                const float* __restrict__ a_dst,
                                                float* __restrict__ alS, float* __restrict__ alD){
    int tid = threadIdx.x;
    int c0 = tid * 4;
    float4 sv = *(const float4*)(a_src + c0);
    float4 dv = *(const float4*)(a_dst + c0);
    int head = tid >> 5, l32 = tid & 31;
    int n0 = blockIdx.x * 16;
    for (int i = 0; i < 16; i++){
        int n = n0 + i;
        uint2 hv = *(const uint2*)(H + (size_t)n*HT + c0);
        float h0,h1,h2,h3;
        unpack2(hv.x, h0, h1); unpack2(hv.y, h2, h3);
        float s = h0*sv.x + h1*sv.y + h2*sv.z + h3*sv.w;
        float d = h0*dv.x + h1*dv.y + h2*dv.z + h3*dv.w;
        #pragma unroll
        for (int of = 16; of; of >>= 1){ s += __shfl_xor(s, of, 32); d += __shfl_xor(d, of, 32); }
        if (l32 == 0){ alS[n*HEADS + head] = s; alD[n*HEADS + head] = d; }
    }
}

/* ---------------- fused segment-softmax + aggregate + bias + relu (v2) ----------------
   Weights precomputed once into LDS; 2 edge-slots x 128 threads, 16B gathers. */
__global__ __launch_bounds__(256) void k_gat_agg(const ushort_t* __restrict__ H, const float* __restrict__ alS,
                                                 const float* __restrict__ alD, const int* __restrict__ offs,
                                                 const int* __restrict__ srcs, const float* __restrict__ bias,
                                                 ushort_t* __restrict__ out){
    int n = blockIdx.x;
    int tid = threadIdx.x;
    int beg = offs[n], end = offs[n+1];
    __shared__ float sm[HEADS], sz[HEADS];
    __shared__ int   sE[AGG_CH];
    __shared__ float wE[AGG_CH][HEADS];
    __shared__ float red[HEADS][128];   /* transposed cross-slot reduce, conflict-free */

    /* phase 1+2: per-head max then sum (32 lanes per head) */
    {
        int head32 = tid >> 5, l32 = tid & 31;
        float ad = alD[n*HEADS + head32];
        float m = -1e30f;
        for (int e = beg + l32; e < end; e += 32){
            float v = alS[srcs[e]*HEADS + head32] + ad;
            v = v > 0.f ? v : NEG*v;
            m = fmaxf(m, v);
        }
        #pragma unroll
        for (int o = 16; o; o >>= 1) m = fmaxf(m, __shfl_xor(m, o, 32));
        float z = 0.f;
        for (int e = beg + l32; e < end; e += 32){
            float v = alS[srcs[e]*HEADS + head32] + ad;
            v = v > 0.f ? v : NEG*v;
            z += __expf(v - m);
        }
        #pragma unroll
        for (int o = 16; o; o >>= 1) z += __shfl_xor(z, o, 32);
        if (l32 == 0){ sm[head32] = m; sz[head32] = z; }
    }
    __syncthreads();

    int slot = tid >> 7;          /* 0 or 1 */
    int lt   = tid & 127;
    int ch0  = lt * 8;
    int head = lt >> 4;
    float acc[8];
    #pragma unroll
    for (int j = 0; j < 8; j++) acc[j] = 0.f;

    for (int cb = beg; cb < end; cb += AGG_CH){
        int cn = min(AGG_CH, end - cb);
        if (tid < cn) sE[tid] = srcs[cb + tid];
        __syncthreads();
        /* compute weights: (edge, head) pairs, 2 per thread */
        #pragma unroll
        for (int r = 0; r < 2; r++){
            int idx = tid + r*256;
            int e = idx >> 3, hd = idx & 7;
            if (e < cn){
                int s = sE[e];
                float v = alS[s*HEADS + hd] + alD[n*HEADS + hd];
                v = v > 0.f ? v : NEG*v;
                wE[e][hd] = __expf(v - sm[hd]) / (sz[hd] + 1e-16f);
            }
        }
        __syncthreads();
        for (int e = slot; e < cn; e += 2){
            int s = sE[e];
            float w = wE[e][head];
            uint4 hv = *(const uint4*)(H + (size_t)s*HT + ch0);
            float f0,f1,f2,f3,f4,f5,f6,f7;
            unpack2(hv.x, f0, f1); unpack2(hv.y, f2, f3);
            unpack2(hv.z, f4, f5); unpack2(hv.w, f6, f7);
            acc[0]+=w*f0; acc[1]+=w*f1; acc[2]+=w*f2; acc[3]+=w*f3;
            acc[4]+=w*f4; acc[5]+=w*f5; acc[6]+=w*f6; acc[7]+=w*f7;
        }
        __syncthreads();
    }
    /* cross-slot reduce (slot1 -> LDS, slot0 adds) */
    if (slot == 1){
        #pragma unroll
        for (int j = 0; j < 8; j++) red[j & 7][lt] = acc[j] + 0.f*red[0][0]; /* keep simple */
    }
    __syncthreads();
    if (slot == 0){
        #pragma unroll
        for (int j = 0; j < 8; j++) acc[j] += red[j][lt];
        float4 bv0 = *(const float4*)(bias + ch0);
        float4 bv1 = *(const float4*)(bias + ch0 + 4);
        float r0 = fmaxf(acc[0]+bv0.x, 0.f), r1 = fmaxf(acc[1]+bv0.y, 0.f);
        float r2 = fmaxf(acc[2]+bv0.z, 0.f), r3 = fmaxf(acc[3]+bv0.w, 0.f);
        float r4 = fmaxf(acc[4]+bv1.x, 0.f), r5 = fmaxf(acc[5]+bv1.y, 0.f);
        float r6 = fmaxf(acc[6]+bv1.z, 0.f), r7 = fmaxf(acc[7]+bv1.w, 0.f);
        uint4 o;
        o.x = (uint32)f2bf(r0) | ((uint32)f2bf(r1) << 16);
        o.y = (uint32)f2bf(r2) | ((uint32)f2bf(r3) << 16);
        o.z = (uint32)f2bf(r4) | ((uint32)f2bf(r5) << 16);
        o.w = (uint32)f2bf(r6) | ((uint32)f2bf(r7) << 16);
        *(uint4*)(out + (size_t)n*HT + ch0) = o;
    }
}

/* ---------------- transpose W2 [1024,1024] -> bf16 [N,K] ---------------- */
__global__ __launch_bounds__(256) void k_transpose(const void* __restrict__ in, const int* __restrict__ flags,
                                                   ushort_t* __restrict__ out){
    __shared__ ushort_t tile[32][33];
    int f32 = flags[1];
    int bx = blockIdx.x, by = blockIdx.y;
    int cx = threadIdx.x & 31;
    int ry = (threadIdx.x >> 5) * 4;
    #pragma unroll
    for (int r = 0; r < 4; r++){
        size_t idx = (size_t)(by*32 + ry + r)*1024 + bx*32 + cx;
        tile[ry + r][cx] = f32 ? f2bf(((const float*)in)[idx]) : ((const ushort_t*)in)[idx];
    }
    __syncthreads();
    #pragma unroll
    for (int r = 0; r < 4; r++)
        out[(size_t)(bx*32 + ry + r)*1024 + by*32 + cx] = tile[cx][ry + r];
}

/* ---------------- layer-2 GEMM: bf16 MFMA ---------------- */
__global__ __launch_bounds__(256) void k_gemm2(const ushort_t* __restrict__ A, const ushort_t* __restrict__ BT,
                                               ushort_t* __restrict__ C){
    __shared__ ushort_t lA[128*32];
    __shared__ ushort_t lB[128*32];
    int tid = threadIdx.x;
    int bm = blockIdx.x, bn = blockIdx.y;
    int lane = tid & 63;
    int wave = tid >> 6;
    int wm = (wave & 1) * 64, wn = (wave >> 1) * 64;
    int lm = lane & 15, kg = lane >> 4;
    f32x4 acc[4][4];
    #pragma unroll
    for (int i = 0; i < 4; i++)
        #pragma unroll
        for (int j = 0; j < 4; j++) acc[i][j] = (f32x4)0.0f;

    const int K = 1024;
    int rowA0 = bm * 128, rowB0 = bn * 128;
    for (int k0 = 0; k0 < K; k0 += 32){
        #pragma unroll
        for (int it = 0; it < 2; ++it){
            int s = tid + it*256;
            int r = s >> 2, ks = s & 3;
            gload_lds16(A  + (size_t)(rowA0 + r)*K + k0 + ks*8, lA + s*8);
            gload_lds16(BT + (size_t)(rowB0 + r)*K + k0 + ks*8, lB + s*8);
        }
        __syncthreads();
        bf16x8 af[4], bfr[4];
        #pragma unroll
        for (int mt = 0; mt < 4; mt++) af[mt]  = *(const bf16x8*)(lA + (wm + mt*16 + lm)*32 + kg*8);
        #pragma unroll
        for (int nt = 0; nt < 4; nt++) bfr[nt] = *(const bf16x8*)(lB + (wn + nt*16 + lm)*32 + kg*8);
        #pragma unroll
        for (int mt = 0; mt < 4; mt++)
            #pragma unroll
            for (int nt = 0; nt < 4; nt++)
                acc[mt][nt] = __builtin_amdgcn_mfma_f32_16x16x32_bf16(af[mt], bfr[nt], acc[mt][nt], 0, 0, 0);
        __syncthreads();
    }
    #pragma unroll
    for (int mt = 0; mt < 4; mt++){
        int row_base = bm*128 + wm + mt*16 + kg*4;
        #pragma unroll
        for (int nt = 0; nt < 4; nt++){
            int col = bn*128 + wn + nt*16 + lm;
            #pragma unroll
            for (int r = 0; r < 4; r++){
                int row = row_base + r;
                if (row < N_NODES) C[(size_t)row*HT + col] = f2bf(acc[mt][nt][r]);
            }
        }
    }
}

/* ---------------- layer-3 GEMM: wave-per-node, W3 in registers ---------------- */
__global__ __launch_bounds__(256) void k_gemm3(const ushort_t* __restrict__ A, const float* __restrict__ W3,
                                               const float* __restrict__ s3,
                                               float* __restrict__ h3, float* __restrict__ al3s, float* __restrict__ al3d){
    int tid = threadIdx.x;
    int lane = tid & 63, wave = tid >> 6;
    int n = blockIdx.x * 4 + wave;
    if (n >= N_NODES) return;
    /* each lane covers channels lane*16 .. lane*16+15 */
    float4 w3r[16];
    #pragma unroll
    for (int j = 0; j < 16; j++) w3r[j] = ((const float4*)W3)[lane*16 + j];
    const uint4* ap = (const uint4*)(A + (size_t)n*HT + lane*16);
    uint4 u0 = ap[0], u1 = ap[1];
    uint32 uu[8] = {u0.x,u0.y,u0.z,u0.w,u1.x,u1.y,u1.z,u1.w};
    float acc0=0.f, acc1=0.f, acc2=0.f, acc3=0.f;
    #pragma unroll
    for (int p = 0; p < 8; p++){
        float lo, hi;
        unpack2(uu[p], lo, hi);
        float4 wl = w3r[p*2], wh = w3r[p*2+1];
        acc0 += lo*wl.x + hi*wh.x;
        acc1 += lo*wl.y + hi*wh.y;
        acc2 += lo*wl.z + hi*wh.z;
        acc3 += lo*wl.w + hi*wh.w;
    }
    #pragma unroll
    for (int o = 32; o; o >>= 1){
        acc0 += __shfl_xor(acc0, o, 64); acc1 += __shfl_xor(acc1, o, 64);
        acc2 += __shfl_xor(acc2, o, 64); acc3 += __shfl_xor(acc3, o, 64);
    }
    if (lane == 0){
        *(float4*)(h3 + n*4) = make_float4(acc0, acc1, acc2, acc3);
        al3s[n] = acc0*s3[0] + acc1*s3[1] + acc2*s3[2] + acc3*s3[3];
        al3d[n] = acc0*s3[16] + acc1*s3[17] + acc2*s3[18] + acc3*s3[19];
    }
}

/* ---------------- layer-3 attention aggregate: wave-per-node ---------------- */
__global__ __launch_bounds__(256) void k_gat_agg3(const float* __restrict__ h3, const float* __restrict__ al3s,
                                                  const float* __restrict__ al3d, const int* __restrict__ offs,
                                                  const int* __restrict__ srcs, const float* __restrict__ b3,
                                                  const int* __restrict__ flags, void* __restrict__ out){
    int tid = threadIdx.x;
    int l = tid & 63, wave = tid >> 6;
    int n = blockIdx.x * 4 + wave;
    if (n >= N_NODES) return;
    int beg = offs[n], end = offs[n+1];
    float ad = al3d[n];
    float m = -1e30f;
    for (int e = beg + l; e < end; e += 64){
        float v = al3s[srcs[e]] + ad; v = v > 0.f ? v : NEG*v;
        m = fmaxf(m, v);
    }
    #pragma unroll
    for (int o = 32; o; o >>= 1) m = fmaxf(m, __shfl_xor(m, o, 64));
    float z = 0.f;
    for (int e = beg + l; e < end; e += 64){
        float v = al3s[srcs[e]] + ad; v = v > 0.f ? v : NEG*v;
        z += __expf(v - m);
    }
    #pragma unroll
    for (int o = 32; o; o >>= 1) z += __shfl_xor(z, o, 64);
    float inv = 1.f / (z + 1e-16f);
    float a0=0.f, a1=0.f, a2=0.f, a3=0.f;
    for (int e = beg + l; e < end; e += 64){
        int s = srcs[e];
        float v = al3s[s] + ad; v = v > 0.f ? v : NEG*v;
        float w = __expf(v - m) * inv;
        float4 hv = *(const float4*)(h3 + s*4);
        a0 += w*hv.x; a1 += w*hv.y; a2 += w*hv.z; a3 += w*hv.w;
    }
    #pragma unroll
    for (int o = 32; o; o >>= 1){
        a0 += __shfl_xor(a0, o, 64); a1 += __shfl_xor(a1, o, 64);
        a2 += __shfl_xor(a2, o, 64); a3 += __shfl_xor(a3, o, 64);
    }
    if (l == 0){
        float r0 = fmaxf(a0 + b3[0], 0.f);
        float r1 = fmaxf(a1 + b3[1], 0.f);
        float r2 = fmaxf(a2 + b3[2], 0.f);
        float r3 = fmaxf(a3 + b3[3], 0.f);
        if (flags[1]){
            float* o4 = (float*)out;
            o4[n*4+0]=r0; o4[n*4+1]=r1; o4[n*4+2]=r2; o4[n*4+3]=r3;
        } else {
            ushort_t* o2 = (ushort_t*)out;
            o2[n*4+0]=f2bf(r0); o2[n*4+1]=f2bf(r1); o2[n*4+2]=f2bf(r2); o2[n*4+3]=f2bf(r3);
        }
    }
}

extern "C" void kernel_launch(void* const* d_in, const int* in_sizes, int n_in,
                              void* d_out, int out_size, void* d_ws, size_t ws_size,
                              hipStream_t stream){
    const void* x   = d_in[0];
    const void* ei  = d_in[1];
    const void* W1  = d_in[2];
    const void* as1 = d_in[3];
    const void* ad1 = d_in[4];
    const void* b1  = d_in[5];
    const void* W2  = d_in[6];
    const void* as2 = d_in[7];
    const void* ad2 = d_in[8];
    const void* b2  = d_in[9];
    const void* W3  = d_in[10];
    const void* as3 = d_in[11];
    const void* ad3 = d_in[12];
    const void* b3  = d_in[13];

    char* ws = (char*)d_ws;
    int* flags     = (int*)(ws + O_FLAG);
    int* srcA      = (int*)(ws + O_SRC);
    int* dstA      = (int*)(ws + O_DST);
    int* counts    = (int*)(ws + O_COUNTS);
    int* offs      = (int*)(ws + O_OFFS);
    int* cursors   = (int*)(ws + O_CURS);
    int* ssort     = (int*)(ws + O_SSORT);
    float* alS     = (float*)(ws + O_ALS);
    float* alD     = (float*)(ws + O_ALD);
    float* al3s    = (float*)(ws + O_AL3S);
    float* al3d    = (float*)(ws + O_AL3D);
    float* h3      = (float*)(ws + O_H3);
    float* xF      = (float*)(ws + O_XF);
    float* W1F     = (float*)(ws + O_W1F);
    float* wvecF   = (float*)(ws + O_AS1F);
    float* W3F     = (float*)(ws + O_W3F);
    float* s3F     = (float*)(ws + O_S3F);
    ushort_t* W2T  = (ushort_t*)(ws + O_W2T);
    ushort_t* bufA = (ushort_t*)(ws + O_BUFA);
    ushort_t* bufB = (ushort_t*)(ws + O_BUFB);

    const int EB = (ET + 255) / 256;

    k_probe<<<1, 64, 0, stream>>>((const int*)ei, (const uint32*)W1, flags);

    CvtArgs ca;
    ca.src[0]=x;   ca.dst[0]=xF;            ca.n[0]=140000;
    ca.src[1]=W1;  ca.dst[1]=W1F;           ca.n[1]=14336;
    ca.src[2]=as1; ca.dst[2]=wvecF+0*1024;  ca.n[2]=1024;
    ca.src[3]=ad1; ca.dst[3]=wvecF+1*1024;  ca.n[3]=1024;
    ca.src[4]=b1;  ca.dst[4]=wvecF+2*1024;  ca.n[4]=1024;
    ca.src[5]=as2; ca.dst[5]=wvecF+3*1024;  ca.n[5]=1024;
    ca.src[6]=ad2; ca.dst[6]=wvecF+4*1024;  ca.n[6]=1024;
    ca.src[7]=b2;  ca.dst[7]=wvecF+5*1024;  ca.n[7]=1024;
    ca.src[8]=W3;  ca.dst[8]=W3F;           ca.n[8]=4096;
    ca.src[9]=as3; ca.dst[9]=s3F+0;         ca.n[9]=4;
    ca.src[10]=ad3; ca.dst[10]=s3F+16;      ca.n[10]=4;
    ca.src[11]=b3;  ca.dst[11]=s3F+32;      ca.n[11]=4;
    k_cvt<<<dim3(137, 12), 256, 0, stream>>>(ca, flags);

    hipMemsetAsync(counts, 0, N_NODES*sizeof(int), stream);
    k_extract_hist<<<EB, 256, 0, stream>>>(ei, flags, srcA, dstA, counts);
    k_scan<<<1, 1024, 0, stream>>>(counts, offs, cursors, N_NODES);
    k_scatter<<<EB, 256, 0, stream>>>(srcA, dstA, cursors, ssort);

    /* layer 1 (gemm + dots fused) */
    k_gemm1f<<<512, 256, 0, stream>>>(xF, W1F, wvecF+0*1024, wvecF+1*1024, bufA, alS, alD);
    k_gat_agg<<<N_NODES, 256, 0, stream>>>(bufA, alS, alD, offs, ssort, wvecF+2*1024, bufB);

    /* layer 2 */
    k_transpose<<<dim3(32, 32), 256, 0, stream>>>(W2, flags, W2T);
    k_gemm2<<<dim3(79, 8), 256, 0, stream>>>(bufB, W2T, bufA);
    k_alpha2<<<625, 256, 0, stream>>>(bufA, wvecF+3*1024, wvecF+4*1024, alS, alD);
    k_gat_agg<<<N_NODES, 256, 0, stream>>>(bufA, alS, alD, offs, ssort, wvecF+5*1024, bufB);

    /* layer 3 */
    k_gemm3<<<2500, 256, 0, stream>>>(bufB, W3F, s3F, h3, al3s, al3d);
    k_gat_agg3<<<2500, 256, 0, stream>>>(h3, al3s, al3d, offs, ssort, s3F+32, flags, d_out);
}